// Round 5
// baseline (361.910 us; speedup 1.0000x reference)
//
#include <hip/hip_runtime.h>
#include <stdint.h>

#define Ttok 1024
#define Hdim 2048
#define Idim 1024
#define Enum 16

typedef __attribute__((ext_vector_type(8))) short  short8;
typedef __attribute__((ext_vector_type(4))) float  f32x4;

__device__ __forceinline__ unsigned short f2bf(float f) {
    union { float f; uint32_t u; } v; v.f = f;
    uint32_t u = v.u;
    return (unsigned short)((u + 0x7FFFu + ((u >> 16) & 1u)) >> 16);
}
__device__ __forceinline__ float bf2f(unsigned short h) {
    union { uint32_t u; float f; } v; v.u = ((uint32_t)h) << 16; return v.f;
}

__device__ __forceinline__ void gld_lds16(const void* g, void* l) {
    __builtin_amdgcn_global_load_lds(
        (const __attribute__((address_space(1))) unsigned int*)g,
        (__attribute__((address_space(3))) unsigned int*)l, 16, 0, 0);
}

// ---------------- Router ----------------
__global__ __launch_bounds__(256) void k_router(
    const float* __restrict__ x, const float* __restrict__ gw,
    const float* __restrict__ bias,
    int* __restrict__ counts, int* __restrict__ tids, float* __restrict__ tws)
{
    __shared__ __align__(16) float xrow[Hdim];
    __shared__ float lg[Enum];
    const int t = blockIdx.x;
    const float* xr = x + (size_t)t * Hdim;

    for (int i = threadIdx.x; i < Hdim / 4; i += 256)
        ((f32x4*)xrow)[i] = ((const f32x4*)xr)[i];
    __syncthreads();

    const int lane = threadIdx.x & 63;
    const int wid  = threadIdx.x >> 6;
    for (int e = wid; e < Enum; e += 4) {
        const float* g = gw + (size_t)e * Hdim;
        float s = 0.f;
        for (int j = lane; j < Hdim; j += 64) s += xrow[j] * g[j];
        #pragma unroll
        for (int off = 32; off; off >>= 1) s += __shfl_xor(s, off);
        if (lane == 0) lg[e] = s;
    }
    __syncthreads();

    if (threadIdx.x == 0) {
        float m = lg[0];
        #pragma unroll
        for (int e = 1; e < Enum; ++e) m = fmaxf(m, lg[e]);
        float sc[Enum]; float sum = 0.f;
        #pragma unroll
        for (int e = 0; e < Enum; ++e) { float ex = expf(lg[e] - m); sc[e] = ex; sum += ex; }
        float inv = 1.f / sum;
        #pragma unroll
        for (int e = 0; e < Enum; ++e) sc[e] *= inv;
        int i0 = 0; float b0 = sc[0] + bias[0];
        #pragma unroll
        for (int e = 1; e < Enum; ++e) { float bb = sc[e] + bias[e]; if (bb > b0) { b0 = bb; i0 = e; } }
        int i1 = -1; float b1 = -1e30f;
        #pragma unroll
        for (int e = 0; e < Enum; ++e) {
            if (e == i0) continue;
            float bb = sc[e] + bias[e]; if (bb > b1) { b1 = bb; i1 = e; }
        }
        float w0 = sc[i0], w1v = sc[i1];
        float winv = 1.f / (w0 + w1v);
        w0 *= winv; w1v *= winv;
        int p0 = atomicAdd(&counts[i0], 1);
        tids[i0 * Ttok + p0] = t; tws[i0 * Ttok + p0] = w0;
        int p1 = atomicAdd(&counts[i1], 1);
        tids[i1 * Ttok + p1] = t; tws[i1 * Ttok + p1] = w1v;
    }
}

// ---------------- Gather: compact + bf16 + tile X ----------------
// Xg tile layout: [pc*256 + kg][row 0..63][8 halfs], kg = k/8. Pad rows zeroed.
__global__ __launch_bounds__(256) void k_gather(
    const float* __restrict__ x, const int* __restrict__ counts,
    const int* __restrict__ tids, unsigned short* __restrict__ Xg)
{
    const int e = blockIdx.y, c = blockIdx.x;
    const int Ne = counts[e];
    if (c * 64 >= Ne) return;
    int poff = 0;
    #pragma unroll
    for (int j = 0; j < Enum; ++j) if (j < e) poff += (counts[j] + 63) >> 6;
    const int pc   = poff + c;
    const int lane = threadIdx.x & 63;
    const int wid  = threadIdx.x >> 6;

    const int r = c * 64 + lane;
    const bool valid = (r < Ne);
    const int tok = valid ? tids[e * Ttok + r] : 0;
    const float* xr = x + (size_t)tok * Hdim;

    for (int kg = wid; kg < 256; kg += 4) {
        short8 v = (short8)0;
        if (valid) {
            f32x4 p0 = *(const f32x4*)(xr + kg * 8);
            f32x4 p1 = *(const f32x4*)(xr + kg * 8 + 4);
            v[0] = (short)f2bf(p0[0]); v[1] = (short)f2bf(p0[1]);
            v[2] = (short)f2bf(p0[2]); v[3] = (short)f2bf(p0[3]);
            v[4] = (short)f2bf(p1[0]); v[5] = (short)f2bf(p1[1]);
            v[6] = (short)f2bf(p1[2]); v[7] = (short)f2bf(p1[3]);
        }
        *(short8*)(Xg + ((size_t)(pc * 256 + kg) * 64 + lane) * 8) = v;
    }
}

// ---------------- Stage 2: H{1,3} = X @ W{1,3} (one mat per block) ----------------
// grid (16 = colblk8 x mat2, 16 chunks, E), block 256. M=64, N=128, BK=32.
union ShW {
    struct {
        unsigned short Xs[2][4][64][8];   // 8 KB  [buf][kg][row][8]
        unsigned short Ws[2][4][128][8];  // 16 KB [buf][kg][col][8]
    } a;
    unsigned short T[64][136];            // 17.4 KB epilogue bounce
};

__global__ __launch_bounds__(256) void k_h(
    const unsigned short* __restrict__ Xg,
    const float* __restrict__ w1, const float* __restrict__ w3,
    const int* __restrict__ counts,
    unsigned short* __restrict__ H1, unsigned short* __restrict__ H3)
{
    const int e  = blockIdx.z;
    const int Ne = counts[e];
    const int c  = blockIdx.y;
    if (c * 64 >= Ne) return;
    int poff = 0;
    #pragma unroll
    for (int j = 0; j < Enum; ++j) if (j < e) poff += (counts[j] + 63) >> 6;
    const int pc     = poff + c;
    const int mat    = blockIdx.x >> 3;
    const int colblk = blockIdx.x & 7;
    const int col0   = colblk * 128;
    const int tid    = threadIdx.x;
    const int lane   = tid & 63;
    const int wid    = tid >> 6;

    __shared__ ShW sh;

    const unsigned short* xsrc = Xg + (size_t)(pc * 256 + wid) * 512 + lane * 8;
    const float* wsrc = (mat ? w3 : w1)
        + ((size_t)e * Hdim + wid * 8) * Idim + col0 + lane * 2;
    unsigned short* Hm = mat ? H3 : H1;

    f32x4 acc[4][2];
    #pragma unroll
    for (int a = 0; a < 4; ++a)
        #pragma unroll
        for (int b = 0; b < 2; ++b) acc[a][b] = (f32x4)(0.f);

    const int NK = Hdim / 32; // 64 steps
    float2 wv[8];
    { // prologue -> buf 0
        #pragma unroll
        for (int j = 0; j < 8; ++j) wv[j] = *(const float2*)(wsrc + (size_t)j * Idim);
        gld_lds16(xsrc, &sh.a.Xs[0][wid][0][0]);
        short8 p0, p1;
        #pragma unroll
        for (int j = 0; j < 8; ++j) { p0[j] = (short)f2bf(wv[j].x); p1[j] = (short)f2bf(wv[j].y); }
        *(short8*)&sh.a.Ws[0][wid][lane * 2][0]     = p0;
        *(short8*)&sh.a.Ws[0][wid][lane * 2 + 1][0] = p1;
    }
    __syncthreads();

    for (int ks = 0; ks < NK; ++ks) {
        const int cur = ks & 1, nxt = cur ^ 1;
        if (ks + 1 < NK) {
            const float* wp = wsrc + (size_t)(ks + 1) * 32 * Idim;
            #pragma unroll
            for (int j = 0; j < 8; ++j) wv[j] = *(const float2*)(wp + (size_t)j * Idim);
            gld_lds16(xsrc + (size_t)(ks + 1) * 4 * 512, &sh.a.Xs[nxt][wid][0][0]);
        }
        {
            const int kgi = lane >> 4;
            short8 a0 = *(const short8*)&sh.a.Xs[cur][kgi][(lane & 15)][0];
            short8 a1 = *(const short8*)&sh.a.Xs[cur][kgi][16 + (lane & 15)][0];
            short8 a2 = *(const short8*)&sh.a.Xs[cur][kgi][32 + (lane & 15)][0];
            short8 a3 = *(const short8*)&sh.a.Xs[cur][kgi][48 + (lane & 15)][0];
            short8 b0 = *(const short8*)&sh.a.Ws[cur][kgi][wid * 32 + (lane & 15)][0];
            short8 b1 = *(const short8*)&sh.a.Ws[cur][kgi][wid * 32 + 16 + (lane & 15)][0];
            acc[0][0] = __builtin_amdgcn_mfma_f32_16x16x32_bf16(a0, b0, acc[0][0], 0, 0, 0);
            acc[0][1] = __builtin_amdgcn_mfma_f32_16x16x32_bf16(a0, b1, acc[0][1], 0, 0, 0);
            acc[1][0] = __builtin_amdgcn_mfma_f32_16x16x32_bf16(a1, b0, acc[1][0], 0, 0, 0);
            acc[1][1] = __builtin_amdgcn_mfma_f32_16x16x32_bf16(a1, b1, acc[1][1], 0, 0, 0);
            acc[2][0] = __builtin_amdgcn_mfma_f32_16x16x32_bf16(a2, b0, acc[2][0], 0, 0, 0);
            acc[2][1] = __builtin_amdgcn_mfma_f32_16x16x32_bf16(a2, b1, acc[2][1], 0, 0, 0);
            acc[3][0] = __builtin_amdgcn_mfma_f32_16x16x32_bf16(a3, b0, acc[3][0], 0, 0, 0);
            acc[3][1] = __builtin_amdgcn_mfma_f32_16x16x32_bf16(a3, b1, acc[3][1], 0, 0, 0);
        }
        if (ks + 1 < NK) {
            short8 p0, p1;
            #pragma unroll
            for (int j = 0; j < 8; ++j) { p0[j] = (short)f2bf(wv[j].x); p1[j] = (short)f2bf(wv[j].y); }
            *(short8*)&sh.a.Ws[nxt][wid][lane * 2][0]     = p0;
            *(short8*)&sh.a.Ws[nxt][wid][lane * 2 + 1][0] = p1;
        }
        __syncthreads();
    }

    // epilogue: acc -> bf16 -> LDS bounce -> H tiled [pc*128+KG][64][8]
    #pragma unroll
    for (int fr = 0; fr < 4; ++fr)
        #pragma unroll
        for (int fc = 0; fc < 2; ++fc)
            #pragma unroll
            for (int k = 0; k < 4; ++k) {
                int row = fr * 16 + ((lane >> 4) << 2) + k;
                int col = wid * 32 + fc * 16 + (lane & 15);
                sh.T[row][col] = f2bf(acc[fr][fc][k]);
            }
    __syncthreads();
    {
        const int row = tid & 63;
        #pragma unroll
        for (int q = 0; q < 4; ++q) {
            int KGl = wid * 4 + q;
            short8 v = *(const short8*)&sh.T[row][KGl * 8];
            *(short8*)(Hm + ((size_t)(pc * 128 + colblk * 16 + KGl) * 64 + row) * 8) = v;
        }
    }
}

// ---------------- Fuse: He = silu(H1) * H3 (tiled, in place layout) ----------------
__global__ __launch_bounds__(256) void k_fuse(
    const unsigned short* __restrict__ H1, const unsigned short* __restrict__ H3,
    const int* __restrict__ counts, unsigned short* __restrict__ He)
{
    const int e = blockIdx.y, c = blockIdx.x;
    const int Ne = counts[e];
    if (c * 64 >= Ne) return;
    int poff = 0;
    #pragma unroll
    for (int j = 0; j < Enum; ++j) if (j < e) poff += (counts[j] + 63) >> 6;
    const size_t base = (size_t)(poff + c) * 128 * 512;

    for (int i = threadIdx.x; i < 128 * 64; i += 256) {
        short8 h1v = *(const short8*)(H1 + base + (size_t)i * 8);
        short8 h3v = *(const short8*)(H3 + base + (size_t)i * 8);
        short8 o;
        #pragma unroll
        for (int j = 0; j < 8; ++j) {
            float h1 = bf2f((unsigned short)h1v[j]);
            float h3 = bf2f((unsigned short)h3v[j]);
            o[j] = (short)f2bf(h1 * h3 / (1.f + expf(-h1)));
        }
        *(short8*)(He + base + (size_t)i * 8) = o;
    }
}

// ---------------- Stage 3: out += w * (He @ W2) ----------------
// grid (Hdim/128=16, 16 chunks, E), block 256. M=64, N=128, BK=32.
__global__ __launch_bounds__(256) void k_o(
    const unsigned short* __restrict__ He,
    const float* __restrict__ w2,
    const int* __restrict__ counts, const int* __restrict__ tids,
    const float* __restrict__ tws,
    float* __restrict__ out)
{
    const int e  = blockIdx.z;
    const int Ne = counts[e];
    const int c  = blockIdx.y;
    if (c * 64 >= Ne) return;
    int poff = 0;
    #pragma unroll
    for (int j = 0; j < Enum; ++j) if (j < e) poff += (counts[j] + 63) >> 6;
    const int pc   = poff + c;
    const int col0 = blockIdx.x * 128;
    const int tid  = threadIdx.x;
    const int lane = tid & 63;
    const int wid  = tid >> 6;

    __shared__ __align__(16) unsigned short Hs[2][4][64][8];   // 8 KB
    __shared__ __align__(16) unsigned short W2s[2][4][128][8]; // 16 KB

    const unsigned short* hsrc = He + (size_t)(pc * 128 + wid) * 512 + lane * 8;
    const float* wsrc = w2 + ((size_t)e * Idim + wid * 8) * Hdim + col0 + lane * 2;

    f32x4 acc[4][2];
    #pragma unroll
    for (int a = 0; a < 4; ++a)
        #pragma unroll
        for (int b = 0; b < 2; ++b) acc[a][b] = (f32x4)(0.f);

    const int NK = Idim / 32; // 32 steps
    float2 wv[8];
    { // prologue
        #pragma unroll
        for (int j = 0; j < 8; ++j) wv[j] = *(const float2*)(wsrc + (size_t)j * Hdim);
        gld_lds16(hsrc, &Hs[0][wid][0][0]);
        short8 p0, p1;
        #pragma unroll
        for (int j = 0; j < 8; ++j) { p0[j] = (short)f2bf(wv[j].x); p1[j] = (short)f2bf(wv[j].y); }
        *(short8*)&W2s[0][wid][lane * 2][0]     = p0;
        *(short8*)&W2s[0][wid][lane * 2 + 1][0] = p1;
    }
    __syncthreads();

    for (int ks = 0; ks < NK; ++ks) {
        const int cur = ks & 1, nxt = cur ^ 1;
        if (ks + 1 < NK) {
            const float* wp = wsrc + (size_t)(ks + 1) * 32 * Hdim;
            #pragma unroll
            for (int j = 0; j < 8; ++j) wv[j] = *(const float2*)(wp + (size_t)j * Hdim);
            gld_lds16(hsrc + (size_t)(ks + 1) * 4 * 512, &Hs[nxt][wid][0][0]);
        }
        {
            const int kgi = lane >> 4;
            short8 a0 = *(const short8*)&Hs[cur][kgi][(lane & 15)][0];
            short8 a1 = *(const short8*)&Hs[cur][kgi][16 + (lane & 15)][0];
            short8 a2 = *(const short8*)&Hs[cur][kgi][32 + (lane & 15)][0];
            short8 a3 = *(const short8*)&Hs[cur][kgi][48 + (lane & 15)][0];
            short8 b0 = *(const short8*)&W2s[cur][kgi][wid * 32 + (lane & 15)][0];
            short8 b1 = *(const short8*)&W2s[cur][kgi][wid * 32 + 16 + (lane & 15)][0];
            acc[0][0] = __builtin_amdgcn_mfma_f32_16x16x32_bf16(a0, b0, acc[0][0], 0, 0, 0);
            acc[0][1] = __builtin_amdgcn_mfma_f32_16x16x32_bf16(a0, b1, acc[0][1], 0, 0, 0);
            acc[1][0] = __builtin_amdgcn_mfma_f32_16x16x32_bf16(a1, b0, acc[1][0], 0, 0, 0);
            acc[1][1] = __builtin_amdgcn_mfma_f32_16x16x32_bf16(a1, b1, acc[1][1], 0, 0, 0);
            acc[2][0] = __builtin_amdgcn_mfma_f32_16x16x32_bf16(a2, b0, acc[2][0], 0, 0, 0);
            acc[2][1] = __builtin_amdgcn_mfma_f32_16x16x32_bf16(a2, b1, acc[2][1], 0, 0, 0);
            acc[3][0] = __builtin_amdgcn_mfma_f32_16x16x32_bf16(a3, b0, acc[3][0], 0, 0, 0);
            acc[3][1] = __builtin_amdgcn_mfma_f32_16x16x32_bf16(a3, b1, acc[3][1], 0, 0, 0);
        }
        if (ks + 1 < NK) {
            short8 p0, p1;
            #pragma unroll
            for (int j = 0; j < 8; ++j) { p0[j] = (short)f2bf(wv[j].x); p1[j] = (short)f2bf(wv[j].y); }
            *(short8*)&W2s[nxt][wid][lane * 2][0]     = p0;
            *(short8*)&W2s[nxt][wid][lane * 2 + 1][0] = p1;
        }
        __syncthreads();
    }

    #pragma unroll
    for (int fr = 0; fr < 4; ++fr) {
        #pragma unroll
        for (int k = 0; k < 4; ++k) {
            int grow = c * 64 + fr * 16 + ((lane >> 4) << 2) + k;
            if (grow < Ne) {
                int   tk = tids[e * Ttok + grow];
                float w  = tws[e * Ttok + grow];
                #pragma unroll
                for (int fc = 0; fc < 2; ++fc) {
                    int col = col0 + wid * 32 + fc * 16 + (lane & 15);
                    atomicAdd(&out[(size_t)tk * Hdim + col], w * acc[fr][fc][k]);
                }
            }
        }
    }
}

extern "C" void kernel_launch(void* const* d_in, const int* in_sizes, int n_in,
                              void* d_out, int out_size, void* d_ws, size_t ws_size,
                              hipStream_t stream)
{
    const float* x    = (const float*)d_in[0];
    const float* gw   = (const float*)d_in[1];
    const float* bias = (const float*)d_in[2];
    const float* w1   = (const float*)d_in[3];
    const float* w3   = (const float*)d_in[4];
    const float* w2   = (const float*)d_in[5];
    float* out = (float*)d_out;

    char* ws = (char*)d_ws;
    int*            counts = (int*)ws;                         // @0        64 B
    int*            tids   = (int*)(ws + 1024);                // @1K       64 KB
    float*          tws    = (float*)(ws + 66560);             // @65K      64 KB
    unsigned short* Xg     = (unsigned short*)(ws + 132096);   // 12.58 MB (48 chunks)
    unsigned short* He     = Xg;                               // alias: Xg dead after k_h
    unsigned short* H1     = (unsigned short*)(ws + 12715008); // 6.29 MB
    unsigned short* H3     = (unsigned short*)(ws + 19006464); // 6.29 MB -> end ~25.3 MB

    hipMemsetAsync(counts, 0, Enum * sizeof(int), stream);
    hipMemsetAsync(out, 0, (size_t)Ttok * Hdim * sizeof(float), stream);

    k_router<<<dim3(Ttok), dim3(256), 0, stream>>>(x, gw, bias, counts, tids, tws);
    k_gather<<<dim3(16, Enum), dim3(256), 0, stream>>>(x, counts, tids, Xg);
    k_h<<<dim3(16, 16, Enum), dim3(256), 0, stream>>>(Xg, w1, w3, counts, H1, H3);
    k_fuse<<<dim3(16, Enum), dim3(256), 0, stream>>>(H1, H3, counts, He);
    k_o<<<dim3(16, 16, Enum), dim3(256), 0, stream>>>(He, w2, counts, tids, tws, out);
}

// Round 6
// 292.432 us; speedup vs baseline: 1.2376x; 1.2376x over previous
//
#include <hip/hip_runtime.h>
#include <stdint.h>

#define Ttok 1024
#define Hdim 2048
#define Idim 1024
#define Enum 16

typedef __attribute__((ext_vector_type(8))) short  short8;
typedef __attribute__((ext_vector_type(4))) float  f32x4;

// barrier WITHOUT vmcnt drain: LDS ops complete, global loads stay in flight
#define BAR() asm volatile("s_waitcnt lgkmcnt(0)\n\ts_barrier" ::: "memory")

__device__ __forceinline__ unsigned short f2bf(float f) {
    union { float f; uint32_t u; } v; v.f = f;
    uint32_t u = v.u;
    return (unsigned short)((u + 0x7FFFu + ((u >> 16) & 1u)) >> 16);
}
__device__ __forceinline__ float bf2f(unsigned short h) {
    union { uint32_t u; float f; } v; v.u = ((uint32_t)h) << 16; return v.f;
}

// ---------------- Router ----------------
__global__ __launch_bounds__(256) void k_router(
    const float* __restrict__ x, const float* __restrict__ gw,
    const float* __restrict__ bias,
    int* __restrict__ counts, int* __restrict__ tids, float* __restrict__ tws)
{
    __shared__ __align__(16) float xrow[Hdim];
    __shared__ float lg[Enum];
    const int t = blockIdx.x;
    const float* xr = x + (size_t)t * Hdim;

    for (int i = threadIdx.x; i < Hdim / 4; i += 256)
        ((f32x4*)xrow)[i] = ((const f32x4*)xr)[i];
    __syncthreads();

    const int lane = threadIdx.x & 63;
    const int wid  = threadIdx.x >> 6;
    for (int e = wid; e < Enum; e += 4) {
        const float* g = gw + (size_t)e * Hdim;
        float s = 0.f;
        for (int j = lane; j < Hdim; j += 64) s += xrow[j] * g[j];
        #pragma unroll
        for (int off = 32; off; off >>= 1) s += __shfl_xor(s, off);
        if (lane == 0) lg[e] = s;
    }
    __syncthreads();

    if (threadIdx.x == 0) {
        float m = lg[0];
        #pragma unroll
        for (int e = 1; e < Enum; ++e) m = fmaxf(m, lg[e]);
        float sc[Enum]; float sum = 0.f;
        #pragma unroll
        for (int e = 0; e < Enum; ++e) { float ex = expf(lg[e] - m); sc[e] = ex; sum += ex; }
        float inv = 1.f / sum;
        #pragma unroll
        for (int e = 0; e < Enum; ++e) sc[e] *= inv;
        int i0 = 0; float b0 = sc[0] + bias[0];
        #pragma unroll
        for (int e = 1; e < Enum; ++e) { float bb = sc[e] + bias[e]; if (bb > b0) { b0 = bb; i0 = e; } }
        int i1 = -1; float b1 = -1e30f;
        #pragma unroll
        for (int e = 0; e < Enum; ++e) {
            if (e == i0) continue;
            float bb = sc[e] + bias[e]; if (bb > b1) { b1 = bb; i1 = e; }
        }
        float w0 = sc[i0], w1v = sc[i1];
        float winv = 1.f / (w0 + w1v);
        w0 *= winv; w1v *= winv;
        int p0 = atomicAdd(&counts[i0], 1);
        tids[i0 * Ttok + p0] = t; tws[i0 * Ttok + p0] = w0;
        int p1 = atomicAdd(&counts[i1], 1);
        tids[i1 * Ttok + p1] = t; tws[i1 * Ttok + p1] = w1v;
    }
}

// ---------------- Gather: compact + bf16 + tile X ----------------
// Xg layout: [pc*256 + kg][row 0..63][8 halfs]; pad rows zeroed. grid (8, 48).
__global__ __launch_bounds__(256) void k_gather(
    const float* __restrict__ x, const int* __restrict__ counts,
    const int* __restrict__ tids, unsigned short* __restrict__ Xg)
{
    const int p = blockIdx.y;
    int pe = -1, c = 0, acc = 0;
    #pragma unroll
    for (int j = 0; j < Enum; ++j) {
        int nj = (counts[j] + 63) >> 6;
        if (pe < 0 && p < acc + nj) { pe = j; c = p - acc; }
        acc += nj;
    }
    if (pe < 0) return;
    const int Ne = counts[pe];
    const int s  = blockIdx.x;          // kg strip: kg in [s*32, s*32+32)
    const int r  = threadIdx.x & 63;
    const int kq = threadIdx.x >> 6;    // 0..3
    const int row = c * 64 + r;
    const bool valid = row < Ne;
    const int tok = valid ? tids[pe * Ttok + row] : 0;
    const float* xr = x + (size_t)tok * Hdim;

    #pragma unroll
    for (int j = 0; j < 8; ++j) {
        int kg = s * 32 + j * 4 + kq;
        short8 v = (short8)0;
        if (valid) {
            f32x4 p0 = *(const f32x4*)(xr + kg * 8);
            f32x4 p1 = *(const f32x4*)(xr + kg * 8 + 4);
            v[0] = (short)f2bf(p0[0]); v[1] = (short)f2bf(p0[1]);
            v[2] = (short)f2bf(p0[2]); v[3] = (short)f2bf(p0[3]);
            v[4] = (short)f2bf(p1[0]); v[5] = (short)f2bf(p1[1]);
            v[6] = (short)f2bf(p1[2]); v[7] = (short)f2bf(p1[3]);
        }
        *(short8*)(Xg + ((size_t)(p * 256 + kg) * 64 + r) * 8) = v;
    }
}

// ---------------- Stage 2: H{1,3} = X @ W{1,3}, pipelined ----------------
// grid (16 = colblk8 x mat2, 16 chunks, E), block 256. M=64, N=128, BK=32, NK=64.
union ShW {
    struct {
        unsigned short Xs[2][4][64][8];   // 8 KB  [buf][kg][row][8]
        unsigned short Ws[2][4][128][8];  // 16 KB [buf][kg][col][8]
    } a;
    unsigned short T[64][136];            // 17.4 KB epilogue bounce
};

__global__ __launch_bounds__(256) void k_h(
    const unsigned short* __restrict__ Xg,
    const float* __restrict__ w1, const float* __restrict__ w3,
    const int* __restrict__ counts,
    unsigned short* __restrict__ H1, unsigned short* __restrict__ H3)
{
    const int e  = blockIdx.z;
    const int Ne = counts[e];
    const int c  = blockIdx.y;
    if (c * 64 >= Ne) return;
    int poff = 0;
    #pragma unroll
    for (int j = 0; j < Enum; ++j) if (j < e) poff += (counts[j] + 63) >> 6;
    const int pc     = poff + c;
    const int mat    = blockIdx.x >> 3;
    const int colblk = blockIdx.x & 7;
    const int col0   = colblk * 128;
    const int tid    = threadIdx.x;
    const int lane   = tid & 63;
    const int wid    = tid >> 6;

    __shared__ ShW sh;

    const unsigned short* xsrc = Xg + (size_t)pc * 131072 + wid * 512 + lane * 8;
    const float* wsrc = (mat ? w3 : w1)
        + ((size_t)e * Hdim + wid * 8) * Idim + col0 + lane * 2;
    unsigned short* Hm = mat ? H3 : H1;

    f32x4 acc[4][2];
    #pragma unroll
    for (int a = 0; a < 4; ++a)
        #pragma unroll
        for (int b = 0; b < 2; ++b) acc[a][b] = (f32x4)(0.f);

    const int NK = Hdim / 32; // 64 (even)

    auto xload = [&](int ks) -> short8 {
        return *(const short8*)(xsrc + (size_t)ks * 2048);
    };
    auto wload = [&](int ks, float2* wv) {
        const float* wp = wsrc + (size_t)ks * 32 * Idim;
        #pragma unroll
        for (int j = 0; j < 8; ++j) wv[j] = *(const float2*)(wp + (size_t)j * Idim);
    };
    auto stage = [&](int buf, short8 xv, const float2* wv) {
        *(short8*)&sh.a.Xs[buf][wid][lane][0] = xv;
        short8 p0, p1;
        #pragma unroll
        for (int j = 0; j < 8; ++j) { p0[j] = (short)f2bf(wv[j].x); p1[j] = (short)f2bf(wv[j].y); }
        *(short8*)&sh.a.Ws[buf][wid][lane * 2][0]     = p0;
        *(short8*)&sh.a.Ws[buf][wid][lane * 2 + 1][0] = p1;
    };
    auto mfma_step = [&](int buf) {
        const int kgi = lane >> 4;
        short8 a0 = *(const short8*)&sh.a.Xs[buf][kgi][(lane & 15)][0];
        short8 a1 = *(const short8*)&sh.a.Xs[buf][kgi][16 + (lane & 15)][0];
        short8 a2 = *(const short8*)&sh.a.Xs[buf][kgi][32 + (lane & 15)][0];
        short8 a3 = *(const short8*)&sh.a.Xs[buf][kgi][48 + (lane & 15)][0];
        short8 b0 = *(const short8*)&sh.a.Ws[buf][kgi][wid * 32 + (lane & 15)][0];
        short8 b1 = *(const short8*)&sh.a.Ws[buf][kgi][wid * 32 + 16 + (lane & 15)][0];
        acc[0][0] = __builtin_amdgcn_mfma_f32_16x16x32_bf16(a0, b0, acc[0][0], 0, 0, 0);
        acc[0][1] = __builtin_amdgcn_mfma_f32_16x16x32_bf16(a0, b1, acc[0][1], 0, 0, 0);
        acc[1][0] = __builtin_amdgcn_mfma_f32_16x16x32_bf16(a1, b0, acc[1][0], 0, 0, 0);
        acc[1][1] = __builtin_amdgcn_mfma_f32_16x16x32_bf16(a1, b1, acc[1][1], 0, 0, 0);
        acc[2][0] = __builtin_amdgcn_mfma_f32_16x16x32_bf16(a2, b0, acc[2][0], 0, 0, 0);
        acc[2][1] = __builtin_amdgcn_mfma_f32_16x16x32_bf16(a2, b1, acc[2][1], 0, 0, 0);
        acc[3][0] = __builtin_amdgcn_mfma_f32_16x16x32_bf16(a3, b0, acc[3][0], 0, 0, 0);
        acc[3][1] = __builtin_amdgcn_mfma_f32_16x16x32_bf16(a3, b1, acc[3][1], 0, 0, 0);
    };

    // prologue: load sets for steps 0,1; stage step 0
    short8 xA = xload(0), xB = xload(1);
    float2 wA[8], wB[8];
    wload(0, wA); wload(1, wB);
    stage(0, xA, wA);
    BAR();

    for (int ks = 0; ks < NK; ks += 2) {
        if (ks + 2 < NK) { xA = xload(ks + 2); wload(ks + 2, wA); }
        mfma_step(0);
        stage(1, xB, wB);
        BAR();
        if (ks + 3 < NK) { xB = xload(ks + 3); wload(ks + 3, wB); }
        mfma_step(1);
        if (ks + 2 < NK) stage(0, xA, wA);
        BAR();
    }

    // epilogue: acc -> bf16 -> LDS bounce -> H tiled [pc*128 + KG][64][8]
    #pragma unroll
    for (int fr = 0; fr < 4; ++fr)
        #pragma unroll
        for (int fc = 0; fc < 2; ++fc)
            #pragma unroll
            for (int k = 0; k < 4; ++k) {
                int row = fr * 16 + ((lane >> 4) << 2) + k;
                int col = wid * 32 + fc * 16 + (lane & 15);
                sh.T[row][col] = f2bf(acc[fr][fc][k]);
            }
    __syncthreads();
    {
        const int row = tid & 63;
        #pragma unroll
        for (int q = 0; q < 4; ++q) {
            int KGl = wid * 4 + q;
            short8 v = *(const short8*)&sh.T[row][KGl * 8];
            *(short8*)(Hm + ((size_t)(pc * 128 + colblk * 16 + KGl) * 64 + row) * 8) = v;
        }
    }
}

// ---------------- Stage 3: out += w * (silu(H1)*H3 @ W2), pipelined ----------------
// grid (16, 16 chunks, E), block 256. M=64, N=128, BK=32, NK=32. Fuse in A-staging.
__global__ __launch_bounds__(256) void k_o(
    const unsigned short* __restrict__ H1, const unsigned short* __restrict__ H3,
    const float* __restrict__ w2,
    const int* __restrict__ counts, const int* __restrict__ tids,
    const float* __restrict__ tws,
    float* __restrict__ out)
{
    const int e  = blockIdx.z;
    const int Ne = counts[e];
    const int c  = blockIdx.y;
    if (c * 64 >= Ne) return;
    int poff = 0;
    #pragma unroll
    for (int j = 0; j < Enum; ++j) if (j < e) poff += (counts[j] + 63) >> 6;
    const int pc   = poff + c;
    const int col0 = blockIdx.x * 128;
    const int tid  = threadIdx.x;
    const int lane = tid & 63;
    const int wid  = tid >> 6;

    __shared__ __align__(16) unsigned short As[2][4][64][8];   // 8 KB
    __shared__ __align__(16) unsigned short Ws[2][4][128][8];  // 16 KB

    const unsigned short* h1src = H1 + (size_t)pc * 65536 + wid * 512 + lane * 8;
    const unsigned short* h3src = H3 + (size_t)pc * 65536 + wid * 512 + lane * 8;
    const float* wsrc = w2 + ((size_t)e * Idim + wid * 8) * Hdim + col0 + lane * 2;

    f32x4 acc[4][2];
    #pragma unroll
    for (int a = 0; a < 4; ++a)
        #pragma unroll
        for (int b = 0; b < 2; ++b) acc[a][b] = (f32x4)(0.f);

    const int NK = Idim / 32; // 32 (even)

    auto hload = [&](int ks, short8& h1v, short8& h3v) {
        h1v = *(const short8*)(h1src + (size_t)ks * 2048);
        h3v = *(const short8*)(h3src + (size_t)ks * 2048);
    };
    auto wload = [&](int ks, float2* wv) {
        const float* wp = wsrc + (size_t)ks * 32 * Hdim;
        #pragma unroll
        for (int j = 0; j < 8; ++j) wv[j] = *(const float2*)(wp + (size_t)j * Hdim);
    };
    auto stage = [&](int buf, short8 h1v, short8 h3v, const float2* wv) {
        short8 he;
        #pragma unroll
        for (int j = 0; j < 8; ++j) {
            float h1 = bf2f((unsigned short)h1v[j]);
            float h3 = bf2f((unsigned short)h3v[j]);
            he[j] = (short)f2bf(h1 * h3 / (1.f + expf(-h1)));
        }
        *(short8*)&As[buf][wid][lane][0] = he;
        short8 p0, p1;
        #pragma unroll
        for (int j = 0; j < 8; ++j) { p0[j] = (short)f2bf(wv[j].x); p1[j] = (short)f2bf(wv[j].y); }
        *(short8*)&Ws[buf][wid][lane * 2][0]     = p0;
        *(short8*)&Ws[buf][wid][lane * 2 + 1][0] = p1;
    };
    auto mfma_step = [&](int buf) {
        const int kgi = lane >> 4;
        short8 a0 = *(const short8*)&As[buf][kgi][(lane & 15)][0];
        short8 a1 = *(const short8*)&As[buf][kgi][16 + (lane & 15)][0];
        short8 a2 = *(const short8*)&As[buf][kgi][32 + (lane & 15)][0];
        short8 a3 = *(const short8*)&As[buf][kgi][48 + (lane & 15)][0];
        short8 b0 = *(const short8*)&Ws[buf][kgi][wid * 32 + (lane & 15)][0];
        short8 b1 = *(const short8*)&Ws[buf][kgi][wid * 32 + 16 + (lane & 15)][0];
        acc[0][0] = __builtin_amdgcn_mfma_f32_16x16x32_bf16(a0, b0, acc[0][0], 0, 0, 0);
        acc[0][1] = __builtin_amdgcn_mfma_f32_16x16x32_bf16(a0, b1, acc[0][1], 0, 0, 0);
        acc[1][0] = __builtin_amdgcn_mfma_f32_16x16x32_bf16(a1, b0, acc[1][0], 0, 0, 0);
        acc[1][1] = __builtin_amdgcn_mfma_f32_16x16x32_bf16(a1, b1, acc[1][1], 0, 0, 0);
        acc[2][0] = __builtin_amdgcn_mfma_f32_16x16x32_bf16(a2, b0, acc[2][0], 0, 0, 0);
        acc[2][1] = __builtin_amdgcn_mfma_f32_16x16x32_bf16(a2, b1, acc[2][1], 0, 0, 0);
        acc[3][0] = __builtin_amdgcn_mfma_f32_16x16x32_bf16(a3, b0, acc[3][0], 0, 0, 0);
        acc[3][1] = __builtin_amdgcn_mfma_f32_16x16x32_bf16(a3, b1, acc[3][1], 0, 0, 0);
    };

    short8 h1A, h3A, h1B, h3B;
    float2 wA[8], wB[8];
    hload(0, h1A, h3A); wload(0, wA);
    hload(1, h1B, h3B); wload(1, wB);
    stage(0, h1A, h3A, wA);
    BAR();

    for (int ks = 0; ks < NK; ks += 2) {
        if (ks + 2 < NK) { hload(ks + 2, h1A, h3A); wload(ks + 2, wA); }
        mfma_step(0);
        stage(1, h1B, h3B, wB);
        BAR();
        if (ks + 3 < NK) { hload(ks + 3, h1B, h3B); wload(ks + 3, wB); }
        mfma_step(1);
        if (ks + 2 < NK) stage(0, h1A, h3A, wA);
        BAR();
    }

    #pragma unroll
    for (int fr = 0; fr < 4; ++fr) {
        #pragma unroll
        for (int k = 0; k < 4; ++k) {
            int grow = c * 64 + fr * 16 + ((lane >> 4) << 2) + k;
            if (grow < Ne) {
                int   tk = tids[e * Ttok + grow];
                float w  = tws[e * Ttok + grow];
                #pragma unroll
                for (int fc = 0; fc < 2; ++fc) {
                    int col = col0 + wid * 32 + fc * 16 + (lane & 15);
                    atomicAdd(&out[(size_t)tk * Hdim + col], w * acc[fr][fc][k]);
                }
            }
        }
    }
}

extern "C" void kernel_launch(void* const* d_in, const int* in_sizes, int n_in,
                              void* d_out, int out_size, void* d_ws, size_t ws_size,
                              hipStream_t stream)
{
    const float* x    = (const float*)d_in[0];
    const float* gw   = (const float*)d_in[1];
    const float* bias = (const float*)d_in[2];
    const float* w1   = (const float*)d_in[3];
    const float* w3   = (const float*)d_in[4];
    const float* w2   = (const float*)d_in[5];
    float* out = (float*)d_out;

    char* ws = (char*)d_ws;
    int*            counts = (int*)ws;                         // @0        64 B
    int*            tids   = (int*)(ws + 1024);                // @1K       64 KB
    float*          tws    = (float*)(ws + 66560);             // @65K      64 KB
    unsigned short* Xg     = (unsigned short*)(ws + 132096);   // 12.58 MB (48 chunks)
    unsigned short* H1     = (unsigned short*)(ws + 12715008); // 6.29 MB
    unsigned short* H3     = (unsigned short*)(ws + 19006464); // 6.29 MB -> end ~25.3 MB

    hipMemsetAsync(counts, 0, Enum * sizeof(int), stream);
    hipMemsetAsync(out, 0, (size_t)Ttok * Hdim * sizeof(float), stream);

    k_router<<<dim3(Ttok), dim3(256), 0, stream>>>(x, gw, bias, counts, tids, tws);
    k_gather<<<dim3(8, 48), dim3(256), 0, stream>>>(x, counts, tids, Xg);
    k_h<<<dim3(16, 16, Enum), dim3(256), 0, stream>>>(Xg, w1, w3, counts, H1, H3);
    k_o<<<dim3(16, 16, Enum), dim3(256), 0, stream>>>(H1, H3, w2, counts, tids, tws, out);
}

// Round 7
// 254.768 us; speedup vs baseline: 1.4205x; 1.1478x over previous
//
#include <hip/hip_runtime.h>
#include <stdint.h>

#define Ttok 1024
#define Hdim 2048
#define Idim 1024
#define Enum 16

typedef __attribute__((ext_vector_type(8))) short  short8;
typedef __attribute__((ext_vector_type(4))) float  f32x4;

// barrier WITHOUT vmcnt drain: LDS ops complete, global loads stay in flight
#define BAR() asm volatile("s_waitcnt lgkmcnt(0)\n\ts_barrier" ::: "memory")

__device__ __forceinline__ unsigned short f2bf(float f) {
    union { float f; uint32_t u; } v; v.f = f;
    uint32_t u = v.u;
    return (unsigned short)((u + 0x7FFFu + ((u >> 16) & 1u)) >> 16);
}
__device__ __forceinline__ float bf2f(unsigned short h) {
    union { uint32_t u; float f; } v; v.u = ((uint32_t)h) << 16; return v.f;
}
// packed f32->bf16 (RNE), 2 values -> 1 dword
__device__ __forceinline__ uint32_t cvtpk(float lo, float hi) {
    uint32_t d;
    asm("v_cvt_pk_bf16_f32 %0, %1, %2" : "=v"(d) : "v"(lo), "v"(hi));
    return d;
}
__device__ __forceinline__ float silu_mul(unsigned short h1u, unsigned short h3u) {
    float h1 = bf2f(h1u), h3 = bf2f(h3u);
    return h1 * h3 * __builtin_amdgcn_rcpf(1.f + __expf(-h1));
}

// ---------------- Router ----------------
__global__ __launch_bounds__(256) void k_router(
    const float* __restrict__ x, const float* __restrict__ gw,
    const float* __restrict__ bias,
    int* __restrict__ counts, int* __restrict__ tids, float* __restrict__ tws)
{
    __shared__ __align__(16) float xrow[Hdim];
    __shared__ float lg[Enum];
    const int t = blockIdx.x;
    const float* xr = x + (size_t)t * Hdim;

    for (int i = threadIdx.x; i < Hdim / 4; i += 256)
        ((f32x4*)xrow)[i] = ((const f32x4*)xr)[i];
    __syncthreads();

    const int lane = threadIdx.x & 63;
    const int wid  = threadIdx.x >> 6;
    for (int e = wid; e < Enum; e += 4) {
        const float* g = gw + (size_t)e * Hdim;
        float s = 0.f;
        for (int j = lane; j < Hdim; j += 64) s += xrow[j] * g[j];
        #pragma unroll
        for (int off = 32; off; off >>= 1) s += __shfl_xor(s, off);
        if (lane == 0) lg[e] = s;
    }
    __syncthreads();

    if (threadIdx.x == 0) {
        float m = lg[0];
        #pragma unroll
        for (int e = 1; e < Enum; ++e) m = fmaxf(m, lg[e]);
        float sc[Enum]; float sum = 0.f;
        #pragma unroll
        for (int e = 0; e < Enum; ++e) { float ex = expf(lg[e] - m); sc[e] = ex; sum += ex; }
        float inv = 1.f / sum;
        #pragma unroll
        for (int e = 0; e < Enum; ++e) sc[e] *= inv;
        int i0 = 0; float b0 = sc[0] + bias[0];
        #pragma unroll
        for (int e = 1; e < Enum; ++e) { float bb = sc[e] + bias[e]; if (bb > b0) { b0 = bb; i0 = e; } }
        int i1 = -1; float b1 = -1e30f;
        #pragma unroll
        for (int e = 0; e < Enum; ++e) {
            if (e == i0) continue;
            float bb = sc[e] + bias[e]; if (bb > b1) { b1 = bb; i1 = e; }
        }
        float w0 = sc[i0], w1v = sc[i1];
        float winv = 1.f / (w0 + w1v);
        w0 *= winv; w1v *= winv;
        int p0 = atomicAdd(&counts[i0], 1);
        tids[i0 * Ttok + p0] = t; tws[i0 * Ttok + p0] = w0;
        int p1 = atomicAdd(&counts[i1], 1);
        tids[i1 * Ttok + p1] = t; tws[i1 * Ttok + p1] = w1v;
    }
}

// ---------------- Gather: compact + bf16 + tile X ----------------
// Xg layout: [pc*256 + kg][row 0..63][8 halfs]; pad rows zeroed. grid (8, 48).
__global__ __launch_bounds__(256) void k_gather(
    const float* __restrict__ x, const int* __restrict__ counts,
    const int* __restrict__ tids, unsigned short* __restrict__ Xg)
{
    const int p = blockIdx.y;
    int pe = -1, c = 0, acc = 0;
    #pragma unroll
    for (int j = 0; j < Enum; ++j) {
        int nj = (counts[j] + 63) >> 6;
        if (pe < 0 && p < acc + nj) { pe = j; c = p - acc; }
        acc += nj;
    }
    if (pe < 0) return;
    const int Ne = counts[pe];
    const int s  = blockIdx.x;          // kg strip: kg in [s*32, s*32+32)
    const int r  = threadIdx.x & 63;
    const int kq = threadIdx.x >> 6;    // 0..3
    const int row = c * 64 + r;
    const bool valid = row < Ne;
    const int tok = valid ? tids[pe * Ttok + row] : 0;
    const float* xr = x + (size_t)tok * Hdim;

    #pragma unroll
    for (int j = 0; j < 8; ++j) {
        int kg = s * 32 + j * 4 + kq;
        uint4 o = make_uint4(0, 0, 0, 0);
        if (valid) {
            f32x4 p0 = *(const f32x4*)(xr + kg * 8);
            f32x4 p1 = *(const f32x4*)(xr + kg * 8 + 4);
            o.x = cvtpk(p0[0], p0[1]); o.y = cvtpk(p0[2], p0[3]);
            o.z = cvtpk(p1[0], p1[1]); o.w = cvtpk(p1[2], p1[3]);
        }
        *(uint4*)(Xg + ((size_t)(p * 256 + kg) * 64 + r) * 8) = o;
    }
}

// ---------------- Stage 2: H{1,3} = X @ W{1,3}, pipelined ----------------
// grid (32 = mat2 x colblk16, 16 chunks, E), block 256. M=64, N=64, BK=64, NK=32.
union ShH {
    struct {
        unsigned short Xs[2][4096];       // 16 KB [buf][kg*512 + row*8 + j]
        unsigned short Ws[2][8][64][8];   // 16 KB [buf][kg][col][j]
    } a;
    unsigned short T[64][80];             // 10.2 KB epilogue bounce
};

__global__ __launch_bounds__(256, 4) void k_h(
    const unsigned short* __restrict__ Xg,
    const float* __restrict__ w1, const float* __restrict__ w3,
    const int* __restrict__ counts,
    unsigned short* __restrict__ H1, unsigned short* __restrict__ H3)
{
    const int e  = blockIdx.z;
    const int Ne = counts[e];
    const int c  = blockIdx.y;
    if (c * 64 >= Ne) return;
    int poff = 0;
    #pragma unroll
    for (int j = 0; j < Enum; ++j) if (j < e) poff += (counts[j] + 63) >> 6;
    const int pc   = poff + c;
    const int mat  = blockIdx.x >> 4;
    const int cb   = blockIdx.x & 15;
    const int col0 = cb * 64;
    const int tid  = threadIdx.x;
    const int lane = tid & 63;
    const int wid  = tid >> 6;
    const int l15  = lane & 15;
    const int kq   = lane >> 4;

    __shared__ ShH sh;

    const unsigned short* xsrc = Xg + (size_t)pc * 131072;
    const int wkg = tid >> 5;            // k-row group (8 rows each)
    const int wcp = (tid & 31) * 2;      // col pair
    const float* wsrc = (mat ? w3 : w1)
        + ((size_t)e * Hdim + wkg * 8) * Idim + col0 + wcp;
    unsigned short* Hm = mat ? H3 : H1;

    f32x4 acc[4];
    #pragma unroll
    for (int a = 0; a < 4; ++a) acc[a] = (f32x4)(0.f);

    const int NK = Hdim / 64; // 32 (even)

    auto xload = [&](int ks, short8& v0, short8& v1) {
        const unsigned short* p = xsrc + (size_t)ks * 4096;
        v0 = *(const short8*)(p + tid * 8);
        v1 = *(const short8*)(p + 2048 + tid * 8);
    };
    auto wload = [&](int ks, float2* wv) {
        const float* wp = wsrc + (size_t)ks * 64 * Idim;
        #pragma unroll
        for (int j = 0; j < 8; ++j) wv[j] = *(const float2*)(wp + (size_t)j * Idim);
    };
    auto stage = [&](int buf, short8 x0, short8 x1, const float2* wv) {
        *(short8*)&sh.a.Xs[buf][tid * 8]        = x0;
        *(short8*)&sh.a.Xs[buf][2048 + tid * 8] = x1;
        uint4 q0, q1;
        q0.x = cvtpk(wv[0].x, wv[1].x); q0.y = cvtpk(wv[2].x, wv[3].x);
        q0.z = cvtpk(wv[4].x, wv[5].x); q0.w = cvtpk(wv[6].x, wv[7].x);
        q1.x = cvtpk(wv[0].y, wv[1].y); q1.y = cvtpk(wv[2].y, wv[3].y);
        q1.z = cvtpk(wv[4].y, wv[5].y); q1.w = cvtpk(wv[6].y, wv[7].y);
        *(uint4*)&sh.a.Ws[buf][wkg][wcp][0]     = q0;
        *(uint4*)&sh.a.Ws[buf][wkg][wcp + 1][0] = q1;
    };
    auto mfma_step = [&](int buf) {
        #pragma unroll
        for (int ks2 = 0; ks2 < 2; ++ks2) {
            const int kgi = ks2 * 4 + kq;
            short8 b = *(const short8*)&sh.a.Ws[buf][kgi][wid * 16 + l15][0];
            #pragma unroll
            for (int fr = 0; fr < 4; ++fr) {
                short8 af = *(const short8*)&sh.a.Xs[buf][kgi * 512 + (fr * 16 + l15) * 8];
                acc[fr] = __builtin_amdgcn_mfma_f32_16x16x32_bf16(af, b, acc[fr], 0, 0, 0);
            }
        }
    };

    short8 xA0, xA1, xB0, xB1;
    float2 wA[8], wB[8];
    xload(0, xA0, xA1); wload(0, wA);
    xload(1, xB0, xB1); wload(1, wB);
    stage(0, xA0, xA1, wA);
    BAR();

    for (int ks = 0; ks < NK; ks += 2) {
        if (ks + 2 < NK) { xload(ks + 2, xA0, xA1); wload(ks + 2, wA); }
        mfma_step(0);
        stage(1, xB0, xB1, wB);
        BAR();
        if (ks + 3 < NK) { xload(ks + 3, xB0, xB1); wload(ks + 3, wB); }
        mfma_step(1);
        if (ks + 2 < NK) stage(0, xA0, xA1, wA);
        BAR();
    }

    // epilogue: acc -> bf16 -> LDS bounce -> H tiled [pc*128 + KG][64][8]
    #pragma unroll
    for (int fr = 0; fr < 4; ++fr)
        #pragma unroll
        for (int k = 0; k < 4; ++k)
            sh.T[fr * 16 + kq * 4 + k][wid * 16 + l15] = f2bf(acc[fr][k]);
    __syncthreads();
    {
        const int r = tid & 63, kgw = tid >> 6;
        #pragma unroll
        for (int q = 0; q < 2; ++q) {
            int KGl = kgw * 2 + q;
            short8 v = *(const short8*)&sh.T[r][KGl * 8];
            *(short8*)(Hm + ((size_t)(pc * 128 + cb * 8 + KGl) * 64 + r) * 8) = v;
        }
    }
}

// ---------------- Stage 3: out += w * (silu(H1)*H3 @ W2), pipelined ----------------
// grid (32, 16 chunks, E), block 256. M=64, N=64, BK=64, NK=16. Fuse in A-staging.
__global__ __launch_bounds__(256, 4) void k_o(
    const unsigned short* __restrict__ H1, const unsigned short* __restrict__ H3,
    const float* __restrict__ w2,
    const int* __restrict__ counts, const int* __restrict__ tids,
    const float* __restrict__ tws,
    float* __restrict__ out)
{
    const int e  = blockIdx.z;
    const int Ne = counts[e];
    const int c  = blockIdx.y;
    if (c * 64 >= Ne) return;
    int poff = 0;
    #pragma unroll
    for (int j = 0; j < Enum; ++j) if (j < e) poff += (counts[j] + 63) >> 6;
    const int pc   = poff + c;
    const int col0 = blockIdx.x * 64;
    const int tid  = threadIdx.x;
    const int lane = tid & 63;
    const int wid  = tid >> 6;
    const int l15  = lane & 15;
    const int kq   = lane >> 4;

    __shared__ __align__(16) unsigned short As[2][4096];      // 16 KB
    __shared__ __align__(16) unsigned short Ws[2][8][64][8];  // 16 KB

    const unsigned short* h1src = H1 + (size_t)pc * 65536;
    const unsigned short* h3src = H3 + (size_t)pc * 65536;
    const int wkg = tid >> 5;
    const int wcp = (tid & 31) * 2;
    const float* wsrc = w2 + ((size_t)e * Idim + wkg * 8) * Hdim + col0 + wcp;

    f32x4 acc[4];
    #pragma unroll
    for (int a = 0; a < 4; ++a) acc[a] = (f32x4)(0.f);

    const int NK = Idim / 64; // 16 (even)

    auto hload = [&](int ks, short8& a0, short8& a1, short8& b0, short8& b1) {
        a0 = *(const short8*)(h1src + (size_t)ks * 4096 + tid * 8);
        a1 = *(const short8*)(h1src + (size_t)ks * 4096 + 2048 + tid * 8);
        b0 = *(const short8*)(h3src + (size_t)ks * 4096 + tid * 8);
        b1 = *(const short8*)(h3src + (size_t)ks * 4096 + 2048 + tid * 8);
    };
    auto wload = [&](int ks, float2* wv) {
        const float* wp = wsrc + (size_t)ks * 64 * Hdim;
        #pragma unroll
        for (int j = 0; j < 8; ++j) wv[j] = *(const float2*)(wp + (size_t)j * Hdim);
    };
    auto stage = [&](int buf, short8 h10, short8 h11, short8 h30, short8 h31,
                     const float2* wv) {
        uint4 o0, o1;
        o0.x = cvtpk(silu_mul(h10[0], h30[0]), silu_mul(h10[1], h30[1]));
        o0.y = cvtpk(silu_mul(h10[2], h30[2]), silu_mul(h10[3], h30[3]));
        o0.z = cvtpk(silu_mul(h10[4], h30[4]), silu_mul(h10[5], h30[5]));
        o0.w = cvtpk(silu_mul(h10[6], h30[6]), silu_mul(h10[7], h30[7]));
        o1.x = cvtpk(silu_mul(h11[0], h31[0]), silu_mul(h11[1], h31[1]));
        o1.y = cvtpk(silu_mul(h11[2], h31[2]), silu_mul(h11[3], h31[3]));
        o1.z = cvtpk(silu_mul(h11[4], h31[4]), silu_mul(h11[5], h31[5]));
        o1.w = cvtpk(silu_mul(h11[6], h31[6]), silu_mul(h11[7], h31[7]));
        *(uint4*)&As[buf][tid * 8]        = o0;
        *(uint4*)&As[buf][2048 + tid * 8] = o1;
        uint4 q0, q1;
        q0.x = cvtpk(wv[0].x, wv[1].x); q0.y = cvtpk(wv[2].x, wv[3].x);
        q0.z = cvtpk(wv[4].x, wv[5].x); q0.w = cvtpk(wv[6].x, wv[7].x);
        q1.x = cvtpk(wv[0].y, wv[1].y); q1.y = cvtpk(wv[2].y, wv[3].y);
        q1.z = cvtpk(wv[4].y, wv[5].y); q1.w = cvtpk(wv[6].y, wv[7].y);
        *(uint4*)&Ws[buf][wkg][wcp][0]     = q0;
        *(uint4*)&Ws[buf][wkg][wcp + 1][0] = q1;
    };
    auto mfma_step = [&](int buf) {
        #pragma unroll
        for (int ks2 = 0; ks2 < 2; ++ks2) {
            const int kgi = ks2 * 4 + kq;
            short8 b = *(const short8*)&Ws[buf][kgi][wid * 16 + l15][0];
            #pragma unroll
            for (int fr = 0; fr < 4; ++fr) {
                short8 af = *(const short8*)&As[buf][kgi * 512 + (fr * 16 + l15) * 8];
                acc[fr] = __builtin_amdgcn_mfma_f32_16x16x32_bf16(af, b, acc[fr], 0, 0, 0);
            }
        }
    };

    short8 h1A0, h1A1, h3A0, h3A1, h1B0, h1B1, h3B0, h3B1;
    float2 wA[8], wB[8];
    hload(0, h1A0, h1A1, h3A0, h3A1); wload(0, wA);
    hload(1, h1B0, h1B1, h3B0, h3B1); wload(1, wB);
    stage(0, h1A0, h1A1, h3A0, h3A1, wA);
    BAR();

    for (int ks = 0; ks < NK; ks += 2) {
        if (ks + 2 < NK) { hload(ks + 2, h1A0, h1A1, h3A0, h3A1); wload(ks + 2, wA); }
        mfma_step(0);
        stage(1, h1B0, h1B1, h3B0, h3B1, wB);
        BAR();
        if (ks + 3 < NK) { hload(ks + 3, h1B0, h1B1, h3B0, h3B1); wload(ks + 3, wB); }
        mfma_step(1);
        if (ks + 2 < NK) stage(0, h1A0, h1A1, h3A0, h3A1, wA);
        BAR();
    }

    #pragma unroll
    for (int fr = 0; fr < 4; ++fr) {
        #pragma unroll
        for (int k = 0; k < 4; ++k) {
            int grow = c * 64 + fr * 16 + kq * 4 + k;
            if (grow < Ne) {
                int   tk = tids[e * Ttok + grow];
                float w  = tws[e * Ttok + grow];
                atomicAdd(&out[(size_t)tk * Hdim + col0 + wid * 16 + l15], w * acc[fr][k]);
            }
        }
    }
}

extern "C" void kernel_launch(void* const* d_in, const int* in_sizes, int n_in,
                              void* d_out, int out_size, void* d_ws, size_t ws_size,
                              hipStream_t stream)
{
    const float* x    = (const float*)d_in[0];
    const float* gw   = (const float*)d_in[1];
    const float* bias = (const float*)d_in[2];
    const float* w1   = (const float*)d_in[3];
    const float* w3   = (const float*)d_in[4];
    const float* w2   = (const float*)d_in[5];
    float* out = (float*)d_out;

    char* ws = (char*)d_ws;
    int*            counts = (int*)ws;                         // @0        64 B
    int*            tids   = (int*)(ws + 1024);                // @1K       64 KB
    float*          tws    = (float*)(ws + 66560);             // @65K      64 KB
    unsigned short* Xg     = (unsigned short*)(ws + 132096);   // 12.58 MB (48 chunks)
    unsigned short* H1     = (unsigned short*)(ws + 12715008); // 6.29 MB
    unsigned short* H3     = (unsigned short*)(ws + 19006464); // 6.29 MB -> end ~25.3 MB

    hipMemsetAsync(counts, 0, Enum * sizeof(int), stream);
    hipMemsetAsync(out, 0, (size_t)Ttok * Hdim * sizeof(float), stream);

    k_router<<<dim3(Ttok), dim3(256), 0, stream>>>(x, gw, bias, counts, tids, tws);
    k_gather<<<dim3(8, 48), dim3(256), 0, stream>>>(x, counts, tids, Xg);
    k_h<<<dim3(32, 16, Enum), dim3(256), 0, stream>>>(Xg, w1, w3, counts, H1, H3);
    k_o<<<dim3(32, 16, Enum), dim3(256), 0, stream>>>(H1, H3, w2, counts, tids, tws, out);
}

// Round 8
// 254.587 us; speedup vs baseline: 1.4216x; 1.0007x over previous
//
#include <hip/hip_runtime.h>
#include <stdint.h>

#define Ttok 1024
#define Hdim 2048
#define Idim 1024
#define Enum 16

typedef __attribute__((ext_vector_type(8))) short  short8;
typedef __attribute__((ext_vector_type(4))) float  f32x4;

// barrier WITHOUT vmcnt drain: LDS ops complete, global loads stay in flight
#define BAR() asm volatile("s_waitcnt lgkmcnt(0)\n\ts_barrier" ::: "memory")

__device__ __forceinline__ unsigned short f2bf(float f) {
    union { float f; uint32_t u; } v; v.f = f;
    uint32_t u = v.u;
    return (unsigned short)((u + 0x7FFFu + ((u >> 16) & 1u)) >> 16);
}
__device__ __forceinline__ float bf2f(unsigned short h) {
    union { uint32_t u; float f; } v; v.u = ((uint32_t)h) << 16; return v.f;
}
// packed f32->bf16 (RNE), 2 values -> 1 dword
__device__ __forceinline__ uint32_t cvtpk(float lo, float hi) {
    uint32_t d;
    asm("v_cvt_pk_bf16_f32 %0, %1, %2" : "=v"(d) : "v"(lo), "v"(hi));
    return d;
}
__device__ __forceinline__ float silu_mul(unsigned short h1u, unsigned short h3u) {
    float h1 = bf2f(h1u), h3 = bf2f(h3u);
    return h1 * h3 * __builtin_amdgcn_rcpf(1.f + __expf(-h1));
}

// ---------------- Router ----------------
__global__ __launch_bounds__(256) void k_router(
    const float* __restrict__ x, const float* __restrict__ gw,
    const float* __restrict__ bias,
    int* __restrict__ counts, int* __restrict__ tids, float* __restrict__ tws)
{
    __shared__ __align__(16) float xrow[Hdim];
    __shared__ float lg[Enum];
    const int t = blockIdx.x;
    const float* xr = x + (size_t)t * Hdim;

    for (int i = threadIdx.x; i < Hdim / 4; i += 256)
        ((f32x4*)xrow)[i] = ((const f32x4*)xr)[i];
    __syncthreads();

    const int lane = threadIdx.x & 63;
    const int wid  = threadIdx.x >> 6;
    for (int e = wid; e < Enum; e += 4) {
        const float* g = gw + (size_t)e * Hdim;
        float s = 0.f;
        for (int j = lane; j < Hdim; j += 64) s += xrow[j] * g[j];
        #pragma unroll
        for (int off = 32; off; off >>= 1) s += __shfl_xor(s, off);
        if (lane == 0) lg[e] = s;
    }
    __syncthreads();

    if (threadIdx.x == 0) {
        float m = lg[0];
        #pragma unroll
        for (int e = 1; e < Enum; ++e) m = fmaxf(m, lg[e]);
        float sc[Enum]; float sum = 0.f;
        #pragma unroll
        for (int e = 0; e < Enum; ++e) { float ex = expf(lg[e] - m); sc[e] = ex; sum += ex; }
        float inv = 1.f / sum;
        #pragma unroll
        for (int e = 0; e < Enum; ++e) sc[e] *= inv;
        int i0 = 0; float b0 = sc[0] + bias[0];
        #pragma unroll
        for (int e = 1; e < Enum; ++e) { float bb = sc[e] + bias[e]; if (bb > b0) { b0 = bb; i0 = e; } }
        int i1 = -1; float b1 = -1e30f;
        #pragma unroll
        for (int e = 0; e < Enum; ++e) {
            if (e == i0) continue;
            float bb = sc[e] + bias[e]; if (bb > b1) { b1 = bb; i1 = e; }
        }
        float w0 = sc[i0], w1v = sc[i1];
        float winv = 1.f / (w0 + w1v);
        w0 *= winv; w1v *= winv;
        int p0 = atomicAdd(&counts[i0], 1);
        tids[i0 * Ttok + p0] = t; tws[i0 * Ttok + p0] = w0;
        int p1 = atomicAdd(&counts[i1], 1);
        tids[i1 * Ttok + p1] = t; tws[i1 * Ttok + p1] = w1v;
    }
}

// ---------------- Gather: compact + bf16 + tile X ----------------
// Xg layout: [pc*256 + kg][row 0..63][8 halfs]; pad rows zeroed. grid (8, 48).
__global__ __launch_bounds__(256) void k_gather(
    const float* __restrict__ x, const int* __restrict__ counts,
    const int* __restrict__ tids, unsigned short* __restrict__ Xg)
{
    const int p = blockIdx.y;
    int pe = -1, c = 0, acc = 0;
    #pragma unroll
    for (int j = 0; j < Enum; ++j) {
        int nj = (counts[j] + 63) >> 6;
        if (pe < 0 && p < acc + nj) { pe = j; c = p - acc; }
        acc += nj;
    }
    if (pe < 0) return;
    const int Ne = counts[pe];
    const int s  = blockIdx.x;          // kg strip: kg in [s*32, s*32+32)
    const int r  = threadIdx.x & 63;
    const int kq = threadIdx.x >> 6;    // 0..3
    const int row = c * 64 + r;
    const bool valid = row < Ne;
    const int tok = valid ? tids[pe * Ttok + row] : 0;
    const float* xr = x + (size_t)tok * Hdim;

    #pragma unroll
    for (int j = 0; j < 8; ++j) {
        int kg = s * 32 + j * 4 + kq;
        uint4 o = make_uint4(0, 0, 0, 0);
        if (valid) {
            f32x4 p0 = *(const f32x4*)(xr + kg * 8);
            f32x4 p1 = *(const f32x4*)(xr + kg * 8 + 4);
            o.x = cvtpk(p0[0], p0[1]); o.y = cvtpk(p0[2], p0[3]);
            o.z = cvtpk(p1[0], p1[1]); o.w = cvtpk(p1[2], p1[3]);
        }
        *(uint4*)(Xg + ((size_t)(p * 256 + kg) * 64 + r) * 8) = o;
    }
}

// ---------------- Stage 2: H{1,3} = X @ W{1,3}, pipelined ----------------
// grid (32 = mat2 x colblk16, 16 chunks, E), block 256. M=64, N=64, BK=64, NK=32.
union ShH {
    struct {
        unsigned short Xs[2][4096];       // 16 KB [buf][kg*512 + row*8 + j]
        unsigned short Ws[2][8][64][8];   // 16 KB [buf][kg][col][j]
    } a;
    unsigned short T[64][80];             // 10.2 KB epilogue bounce
};

__global__ __launch_bounds__(256, 4) void k_h(
    const unsigned short* __restrict__ Xg,
    const float* __restrict__ w1, const float* __restrict__ w3,
    const int* __restrict__ counts,
    unsigned short* __restrict__ H1, unsigned short* __restrict__ H3)
{
    const int e  = blockIdx.z;
    const int Ne = counts[e];
    const int c  = blockIdx.y;
    if (c * 64 >= Ne) return;
    int poff = 0;
    #pragma unroll
    for (int j = 0; j < Enum; ++j) if (j < e) poff += (counts[j] + 63) >> 6;
    const int pc   = poff + c;
    const int mat  = blockIdx.x >> 4;
    const int cb   = blockIdx.x & 15;
    const int col0 = cb * 64;
    const int tid  = threadIdx.x;
    const int lane = tid & 63;
    const int wid  = tid >> 6;
    const int l15  = lane & 15;
    const int kq   = lane >> 4;

    __shared__ ShH sh;

    const unsigned short* xsrc = Xg + (size_t)pc * 131072;
    const int wkg = tid >> 5;            // k-row group (8 rows each)
    const int wcp = (tid & 31) * 2;      // col pair
    const float* wsrc = (mat ? w3 : w1)
        + ((size_t)e * Hdim + wkg * 8) * Idim + col0 + wcp;
    unsigned short* Hm = mat ? H3 : H1;

    f32x4 acc[4];
    #pragma unroll
    for (int a = 0; a < 4; ++a) acc[a] = (f32x4)(0.f);

    const int NK = Hdim / 64; // 32 (even)

    auto xload = [&](int ks, short8& v0, short8& v1) {
        const unsigned short* p = xsrc + (size_t)ks * 4096;
        v0 = *(const short8*)(p + tid * 8);
        v1 = *(const short8*)(p + 2048 + tid * 8);
    };
    auto wload = [&](int ks, float2* wv) {
        const float* wp = wsrc + (size_t)ks * 64 * Idim;
        #pragma unroll
        for (int j = 0; j < 8; ++j) wv[j] = *(const float2*)(wp + (size_t)j * Idim);
    };
    auto stage = [&](int buf, short8 x0, short8 x1, const float2* wv) {
        *(short8*)&sh.a.Xs[buf][tid * 8]        = x0;
        *(short8*)&sh.a.Xs[buf][2048 + tid * 8] = x1;
        uint4 q0, q1;
        q0.x = cvtpk(wv[0].x, wv[1].x); q0.y = cvtpk(wv[2].x, wv[3].x);
        q0.z = cvtpk(wv[4].x, wv[5].x); q0.w = cvtpk(wv[6].x, wv[7].x);
        q1.x = cvtpk(wv[0].y, wv[1].y); q1.y = cvtpk(wv[2].y, wv[3].y);
        q1.z = cvtpk(wv[4].y, wv[5].y); q1.w = cvtpk(wv[6].y, wv[7].y);
        *(uint4*)&sh.a.Ws[buf][wkg][wcp][0]     = q0;
        *(uint4*)&sh.a.Ws[buf][wkg][wcp + 1][0] = q1;
    };
    auto mfma_step = [&](int buf) {
        #pragma unroll
        for (int ks2 = 0; ks2 < 2; ++ks2) {
            const int kgi = ks2 * 4 + kq;
            short8 b = *(const short8*)&sh.a.Ws[buf][kgi][wid * 16 + l15][0];
            #pragma unroll
            for (int fr = 0; fr < 4; ++fr) {
                short8 af = *(const short8*)&sh.a.Xs[buf][kgi * 512 + (fr * 16 + l15) * 8];
                acc[fr] = __builtin_amdgcn_mfma_f32_16x16x32_bf16(af, b, acc[fr], 0, 0, 0);
            }
        }
    };

    short8 xA0, xA1, xB0, xB1;
    float2 wA[8], wB[8];
    xload(0, xA0, xA1); wload(0, wA);
    xload(1, xB0, xB1); wload(1, wB);
    stage(0, xA0, xA1, wA);
    BAR();

    for (int ks = 0; ks < NK; ks += 2) {
        if (ks + 2 < NK) { xload(ks + 2, xA0, xA1); wload(ks + 2, wA); }
        mfma_step(0);
        stage(1, xB0, xB1, wB);
        BAR();
        if (ks + 3 < NK) { xload(ks + 3, xB0, xB1); wload(ks + 3, wB); }
        mfma_step(1);
        if (ks + 2 < NK) stage(0, xA0, xA1, wA);
        BAR();
    }

    // epilogue: acc -> bf16 -> LDS bounce -> H tiled [pc*128 + KG][64][8]
    #pragma unroll
    for (int fr = 0; fr < 4; ++fr)
        #pragma unroll
        for (int k = 0; k < 4; ++k)
            sh.T[fr * 16 + kq * 4 + k][wid * 16 + l15] = f2bf(acc[fr][k]);
    __syncthreads();
    {
        const int r = tid & 63, kgw = tid >> 6;
        #pragma unroll
        for (int q = 0; q < 2; ++q) {
            int KGl = kgw * 2 + q;
            short8 v = *(const short8*)&sh.T[r][KGl * 8];
            *(short8*)(Hm + ((size_t)(pc * 128 + cb * 8 + KGl) * 64 + r) * 8) = v;
        }
    }
}

// ---------------- Stage 3: out += w * (silu(H1)*H3 @ W2), pipelined ----------------
// grid (32, 16 chunks, E), block 256. M=64, N=64, BK=64, NK=16. Fuse in A-staging.
__global__ __launch_bounds__(256, 4) void k_o(
    const unsigned short* __restrict__ H1, const unsigned short* __restrict__ H3,
    const float* __restrict__ w2,
    const int* __restrict__ counts, const int* __restrict__ tids,
    const float* __restrict__ tws,
    float* __restrict__ out)
{
    const int e  = blockIdx.z;
    const int Ne = counts[e];
    const int c  = blockIdx.y;
    if (c * 64 >= Ne) return;
    int poff = 0;
    #pragma unroll
    for (int j = 0; j < Enum; ++j) if (j < e) poff += (counts[j] + 63) >> 6;
    const int pc   = poff + c;
    const int col0 = blockIdx.x * 64;
    const int tid  = threadIdx.x;
    const int lane = tid & 63;
    const int wid  = tid >> 6;
    const int l15  = lane & 15;
    const int kq   = lane >> 4;

    __shared__ __align__(16) unsigned short As[2][4096];      // 16 KB
    __shared__ __align__(16) unsigned short Ws[2][8][64][8];  // 16 KB

    const unsigned short* h1src = H1 + (size_t)pc * 65536;
    const unsigned short* h3src = H3 + (size_t)pc * 65536;
    const int wkg = tid >> 5;
    const int wcp = (tid & 31) * 2;
    const float* wsrc = w2 + ((size_t)e * Idim + wkg * 8) * Hdim + col0 + wcp;

    f32x4 acc[4];
    #pragma unroll
    for (int a = 0; a < 4; ++a) acc[a] = (f32x4)(0.f);

    const int NK = Idim / 64; // 16 (even)

    auto hload = [&](int ks, short8& a0, short8& a1, short8& b0, short8& b1) {
        a0 = *(const short8*)(h1src + (size_t)ks * 4096 + tid * 8);
        a1 = *(const short8*)(h1src + (size_t)ks * 4096 + 2048 + tid * 8);
        b0 = *(const short8*)(h3src + (size_t)ks * 4096 + tid * 8);
        b1 = *(const short8*)(h3src + (size_t)ks * 4096 + 2048 + tid * 8);
    };
    auto wload = [&](int ks, float2* wv) {
        const float* wp = wsrc + (size_t)ks * 64 * Hdim;
        #pragma unroll
        for (int j = 0; j < 8; ++j) wv[j] = *(const float2*)(wp + (size_t)j * Hdim);
    };
    auto stage = [&](int buf, short8 h10, short8 h11, short8 h30, short8 h31,
                     const float2* wv) {
        uint4 o0, o1;
        o0.x = cvtpk(silu_mul(h10[0], h30[0]), silu_mul(h10[1], h30[1]));
        o0.y = cvtpk(silu_mul(h10[2], h30[2]), silu_mul(h10[3], h30[3]));
        o0.z = cvtpk(silu_mul(h10[4], h30[4]), silu_mul(h10[5], h30[5]));
        o0.w = cvtpk(silu_mul(h10[6], h30[6]), silu_mul(h10[7], h30[7]));
        o1.x = cvtpk(silu_mul(h11[0], h31[0]), silu_mul(h11[1], h31[1]));
        o1.y = cvtpk(silu_mul(h11[2], h31[2]), silu_mul(h11[3], h31[3]));
        o1.z = cvtpk(silu_mul(h11[4], h31[4]), silu_mul(h11[5], h31[5]));
        o1.w = cvtpk(silu_mul(h11[6], h31[6]), silu_mul(h11[7], h31[7]));
        *(uint4*)&As[buf][tid * 8]        = o0;
        *(uint4*)&As[buf][2048 + tid * 8] = o1;
        uint4 q0, q1;
        q0.x = cvtpk(wv[0].x, wv[1].x); q0.y = cvtpk(wv[2].x, wv[3].x);
        q0.z = cvtpk(wv[4].x, wv[5].x); q0.w = cvtpk(wv[6].x, wv[7].x);
        q1.x = cvtpk(wv[0].y, wv[1].y); q1.y = cvtpk(wv[2].y, wv[3].y);
        q1.z = cvtpk(wv[4].y, wv[5].y); q1.w = cvtpk(wv[6].y, wv[7].y);
        *(uint4*)&Ws[buf][wkg][wcp][0]     = q0;
        *(uint4*)&Ws[buf][wkg][wcp + 1][0] = q1;
    };
    auto mfma_step = [&](int buf) {
        #pragma unroll
        for (int ks2 = 0; ks2 < 2; ++ks2) {
            const int kgi = ks2 * 4 + kq;
            short8 b = *(const short8*)&Ws[buf][kgi][wid * 16 + l15][0];
            #pragma unroll
            for (int fr = 0; fr < 4; ++fr) {
                short8 af = *(const short8*)&As[buf][kgi * 512 + (fr * 16 + l15) * 8];
                acc[fr] = __builtin_amdgcn_mfma_f32_16x16x32_bf16(af, b, acc[fr], 0, 0, 0);
            }
        }
    };

    short8 h1A0, h1A1, h3A0, h3A1, h1B0, h1B1, h3B0, h3B1;
    float2 wA[8], wB[8];
    hload(0, h1A0, h1A1, h3A0, h3A1); wload(0, wA);
    hload(1, h1B0, h1B1, h3B0, h3B1); wload(1, wB);
    stage(0, h1A0, h1A1, h3A0, h3A1, wA);
    BAR();

    for (int ks = 0; ks < NK; ks += 2) {
        if (ks + 2 < NK) { hload(ks + 2, h1A0, h1A1, h3A0, h3A1); wload(ks + 2, wA); }
        mfma_step(0);
        stage(1, h1B0, h1B1, h3B0, h3B1, wB);
        BAR();
        if (ks + 3 < NK) { hload(ks + 3, h1B0, h1B1, h3B0, h3B1); wload(ks + 3, wB); }
        mfma_step(1);
        if (ks + 2 < NK) stage(0, h1A0, h1A1, h3A0, h3A1, wA);
        BAR();
    }

    #pragma unroll
    for (int fr = 0; fr < 4; ++fr) {
        #pragma unroll
        for (int k = 0; k < 4; ++k) {
            int grow = c * 64 + fr * 16 + kq * 4 + k;
            if (grow < Ne) {
                int   tk = tids[e * Ttok + grow];
                float w  = tws[e * Ttok + grow];
                atomicAdd(&out[(size_t)tk * Hdim + col0 + wid * 16 + l15], w * acc[fr][k]);
            }
        }
    }
}

extern "C" void kernel_launch(void* const* d_in, const int* in_sizes, int n_in,
                              void* d_out, int out_size, void* d_ws, size_t ws_size,
                              hipStream_t stream)
{
    const float* x    = (const float*)d_in[0];
    const float* gw   = (const float*)d_in[1];
    const float* bias = (const float*)d_in[2];
    const float* w1   = (const float*)d_in[3];
    const float* w3   = (const float*)d_in[4];
    const float* w2   = (const float*)d_in[5];
    float* out = (float*)d_out;

    char* ws = (char*)d_ws;
    int*            counts = (int*)ws;                         // @0        64 B
    int*            tids   = (int*)(ws + 1024);                // @1K       64 KB
    float*          tws    = (float*)(ws + 66560);             // @65K      64 KB
    unsigned short* Xg     = (unsigned short*)(ws + 132096);   // 12.58 MB (48 chunks)
    unsigned short* H1     = (unsigned short*)(ws + 12715008); // 6.29 MB
    unsigned short* H3     = (unsigned short*)(ws + 19006464); // 6.29 MB -> end ~25.3 MB

    hipMemsetAsync(counts, 0, Enum * sizeof(int), stream);
    hipMemsetAsync(out, 0, (size_t)Ttok * Hdim * sizeof(float), stream);

    k_router<<<dim3(Ttok), dim3(256), 0, stream>>>(x, gw, bias, counts, tids, tws);
    k_gather<<<dim3(8, 48), dim3(256), 0, stream>>>(x, counts, tids, Xg);
    k_h<<<dim3(32, 16, Enum), dim3(256), 0, stream>>>(Xg, w1, w3, counts, H1, H3);
    k_o<<<dim3(32, 16, Enum), dim3(256), 0, stream>>>(H1, H3, w2, counts, tids, tws, out);
}